// Round 1
// baseline (313.392 us; speedup 1.0000x reference)
//
#include <hip/hip_runtime.h>

// WassersteinLoss: sum over rows of |real - gen| for the prefix strictly
// before the first END_TOKEN (==2.0f) in real. real values are small ints as
// fp32, so exact == compare is safe. Expected prefix ~49 of 4096 elements
// (P(end)=1/50), so early-exit row scan reads ~1/13 of the data.

#define BATCH 8192
#define SEQ   4096
#define END_TOKEN_F 2.0f

__global__ __launch_bounds__(256) void wass_kernel(
    const float* __restrict__ real,
    const float* __restrict__ gen,
    float* __restrict__ out)
{
    const int wave = threadIdx.x >> 6;      // 4 waves per block
    const int lane = threadIdx.x & 63;
    const int row  = blockIdx.x * 4 + wave; // one wave per row
    const size_t row_off = (size_t)row * SEQ;
    const float* rrow = real + row_off;
    const float* grow = gen  + row_off;

    float sum = 0.0f;
    constexpr int CHUNK = 256;              // 64 lanes x float4

    for (int base = 0; base < SEQ; base += CHUNK) {
        const float4 r4 = *reinterpret_cast<const float4*>(rrow + base + lane * 4);

        // first end-token position within this lane's 4 elements (4 = none)
        int local_end = 4;
        if      (r4.x == END_TOKEN_F) local_end = 0;
        else if (r4.y == END_TOKEN_F) local_end = 1;
        else if (r4.z == END_TOKEN_F) local_end = 2;
        else if (r4.w == END_TOKEN_F) local_end = 3;

        const unsigned long long bal = __ballot(local_end < 4);

        int end_pos = CHUNK;                // chunk-relative first end position
        if (bal) {
            const int first_lane = (int)__builtin_ctzll(bal);
            const int le = __shfl(local_end, first_lane, 64);
            end_pos = first_lane * 4 + le;
        }

        const int p = lane * 4;
        if (p < end_pos) {
            const float4 g4 = *reinterpret_cast<const float4*>(grow + base + lane * 4);
            sum += fabsf(r4.x - g4.x);
            if (p + 1 < end_pos) sum += fabsf(r4.y - g4.y);
            if (p + 2 < end_pos) sum += fabsf(r4.z - g4.z);
            if (p + 3 < end_pos) sum += fabsf(r4.w - g4.w);
        }

        if (bal) break;                     // end token found: rest of row is masked
    }

    // wave-level reduction (width 64)
    for (int off = 32; off > 0; off >>= 1)
        sum += __shfl_down(sum, off, 64);

    if (lane == 0)
        atomicAdd(out, sum);
}

extern "C" void kernel_launch(void* const* d_in, const int* in_sizes, int n_in,
                              void* d_out, int out_size, void* d_ws, size_t ws_size,
                              hipStream_t stream)
{
    const float* real = (const float*)d_in[0];
    const float* gen  = (const float*)d_in[1];
    float* out = (float*)d_out;

    // d_out is poisoned to 0xAA before every timed call — zero it on-stream
    // (memset node is graph-capture legal).
    hipMemsetAsync(out, 0, sizeof(float), stream);

    wass_kernel<<<BATCH / 4, 256, 0, stream>>>(real, gen, out);
}

// Round 2
// 213.042 us; speedup vs baseline: 1.4710x; 1.4710x over previous
//
#include <hip/hip_runtime.h>

// WassersteinLoss: sum over rows of |real - gen| for the prefix strictly
// before the first END_TOKEN (==2.0f) in real. real values are small ints as
// fp32, so exact == compare is safe. Expected prefix ~49 of 4096 elements
// (P(end)=1/50): ~99.4% of rows finish in one 256-element chunk.
//
// R1 lesson: one atomicAdd per row (8192 same-address atomics) serialized at
// ~32 cyc each = 109 us with all pipes idle. R2: block-reduce to d_ws
// partials (no atomics), second tiny kernel reduces 2048 partials.

#define BATCH 8192
#define SEQ   4096
#define END_TOKEN_F 2.0f
#define WAVES_PER_BLOCK 4
#define GRID1 (BATCH / WAVES_PER_BLOCK)   // 2048 blocks, one row per wave

__global__ __launch_bounds__(256) void wass_stage1(
    const float* __restrict__ real,
    const float* __restrict__ gen,
    float* __restrict__ partials)
{
    const int wave = threadIdx.x >> 6;
    const int lane = threadIdx.x & 63;
    const int row  = blockIdx.x * WAVES_PER_BLOCK + wave;
    const size_t row_off = (size_t)row * SEQ;
    const float* rrow = real + row_off;
    const float* grow = gen  + row_off;

    float sum = 0.0f;
    constexpr int CHUNK = 256;              // 64 lanes x float4

    for (int base = 0; base < SEQ; base += CHUNK) {
        const float4 r4 = *reinterpret_cast<const float4*>(rrow + base + lane * 4);
        // Issue the gen load up front too: it's needed with ~99.4% probability
        // for the first chunk, and hiding it behind the ballot saves a full
        // dependent-latency round trip.
        const float4 g4 = *reinterpret_cast<const float4*>(grow + base + lane * 4);

        int local_end = 4;                  // first end-token in this lane (4 = none)
        if      (r4.x == END_TOKEN_F) local_end = 0;
        else if (r4.y == END_TOKEN_F) local_end = 1;
        else if (r4.z == END_TOKEN_F) local_end = 2;
        else if (r4.w == END_TOKEN_F) local_end = 3;

        const unsigned long long bal = __ballot(local_end < 4);

        int end_pos = CHUNK;                // chunk-relative first end position
        if (bal) {
            const int first_lane = (int)__builtin_ctzll(bal);
            const int le = __shfl(local_end, first_lane, 64);
            end_pos = first_lane * 4 + le;
        }

        const int p = lane * 4;
        if (p     < end_pos) sum += fabsf(r4.x - g4.x);
        if (p + 1 < end_pos) sum += fabsf(r4.y - g4.y);
        if (p + 2 < end_pos) sum += fabsf(r4.z - g4.z);
        if (p + 3 < end_pos) sum += fabsf(r4.w - g4.w);

        if (bal) break;                     // rest of row is masked
    }

    // wave-level reduction (width 64)
    for (int off = 32; off > 0; off >>= 1)
        sum += __shfl_down(sum, off, 64);

    // block-level: 4 wave partials -> 1 value, plain store (no atomics)
    __shared__ float wsum[WAVES_PER_BLOCK];
    if (lane == 0) wsum[wave] = sum;
    __syncthreads();
    if (threadIdx.x == 0)
        partials[blockIdx.x] = wsum[0] + wsum[1] + wsum[2] + wsum[3];
}

__global__ __launch_bounds__(256) void wass_stage2(
    const float* __restrict__ partials,
    float* __restrict__ out)
{
    const int tid  = threadIdx.x;
    const int lane = tid & 63;
    const int wave = tid >> 6;

    // 2048 partials / 256 threads = 8 each (two float4)
    const float4 a = *reinterpret_cast<const float4*>(partials + tid * 8);
    const float4 b = *reinterpret_cast<const float4*>(partials + tid * 8 + 4);
    float sum = (a.x + a.y) + (a.z + a.w) + (b.x + b.y) + (b.z + b.w);

    for (int off = 32; off > 0; off >>= 1)
        sum += __shfl_down(sum, off, 64);

    __shared__ float wsum[4];
    if (lane == 0) wsum[wave] = sum;
    __syncthreads();
    if (tid == 0)
        *out = wsum[0] + wsum[1] + wsum[2] + wsum[3];
}

extern "C" void kernel_launch(void* const* d_in, const int* in_sizes, int n_in,
                              void* d_out, int out_size, void* d_ws, size_t ws_size,
                              hipStream_t stream)
{
    const float* real = (const float*)d_in[0];
    const float* gen  = (const float*)d_in[1];
    float* out      = (float*)d_out;
    float* partials = (float*)d_ws;         // 2048 floats = 8 KB

    wass_stage1<<<GRID1, 256, 0, stream>>>(real, gen, partials);
    wass_stage2<<<1, 256, 0, stream>>>(partials, out);
}